// Round 3
// baseline (1946.256 us; speedup 1.0000x reference)
//
#include <hip/hip_runtime.h>

// Persistent systolic ConvLSTM2D x2. B=4 T=16 H=W=64 Cin=F=32, k=3 SAME.
// 512 blocks = {layer 0/1} x {256 rows (b,y)}; each block runs 16 timestep
// phases for its row. Waves = {src x/h} x {f-half}; each wave holds its 36
// weight fragments in VGPRs for the whole kernel. Cell state c in registers.
// Cross-row/layer sync via per-row monotonic flags (agent-scope atomics).

typedef __bf16 bf16x8 __attribute__((ext_vector_type(8)));
typedef float f32x4 __attribute__((ext_vector_type(4)));

#define WPK_ELEMS 73728   // 18 kchunks * 8 ntiles * 64 lanes * 8
#define PLANE 524288      // 4*64*64*32 elems (one parity plane)

__device__ __forceinline__ float fsigmoid(float z) {
    return 1.0f / (1.0f + __expf(-z));
}
__device__ __forceinline__ float ftanh(float z) {
    z = fminf(15.0f, fmaxf(-15.0f, z));
    float e = __expf(2.0f * z);
    return (e - 1.0f) / (e + 1.0f);
}

// Pack wk/wr (3,3,32,128) fp32 -> wpk[layer][cix][nt][lane][j2] bf16.
// cix = tap*2 + src (src0 = input kernel, src1 = recurrent kernel).
// col n' = nt*16 + (lane&15): gate = nt&3, f = (nt>>2)*16 + (lane&15).
__global__ __launch_bounds__(256) void pack_weights(
    const float* __restrict__ wk1, const float* __restrict__ wr1,
    const float* __restrict__ wk2, const float* __restrict__ wr2,
    __bf16* __restrict__ wpk)
{
    int i = blockIdx.x * 256 + threadIdx.x;
    if (i >= 2 * WPK_ELEMS) return;
    int layer = i / WPK_ELEMS;
    int r = i - layer * WPK_ELEMS;
    int j2 = r & 7;
    int L  = (r >> 3) & 63;
    int nt = (r >> 9) & 7;
    int cix = r >> 12;            // 0..17
    int tap = cix >> 1, src = cix & 1;
    int s = ((L >> 4) << 3) + j2;            // channel 0..31
    int gate = nt & 3;
    int f = ((nt >> 2) << 4) + (L & 15);
    int n = (gate << 5) + f;
    const float* w = layer ? (src ? wr2 : wk2) : (src ? wr1 : wk1);
    wpk[i] = (__bf16)w[(tap * 32 + s) * 128 + n];
}

__device__ __forceinline__ void waitflag(const int* p, int target) {
    if (target <= 0) return;
    int guard = 0;
    while (__hip_atomic_load(p, __ATOMIC_RELAXED, __HIP_MEMORY_SCOPE_AGENT) < target) {
        __builtin_amdgcn_s_sleep(2);
        if (++guard > 50000000) return;   // bail -> wrong result, never a hang
    }
}

__global__ __launch_bounds__(256, 2) void clstm_persist(
    const float* __restrict__ x,          // (4,16,64,64,32) fp32
    const __bf16* __restrict__ wpk1,
    const __bf16* __restrict__ wpk2,
    const float* __restrict__ bias1,
    const float* __restrict__ bias2,
    __bf16* __restrict__ h1b,             // 2 parity planes of (4,64,64,32)
    __bf16* __restrict__ h2b,             // 2 parity planes
    int* __restrict__ flag1,              // 256 rows
    int* __restrict__ flag2,
    float* __restrict__ out)              // (4,16,64,64,32) fp32
{
    __shared__ __bf16 s_x[3 * 66 * 36];   // src0 tile (x or h1_t), 36-ch padded
    __shared__ __bf16 s_h[3 * 66 * 36];   // src1 tile (h_{t-1})
    __shared__ f32x4  s_red[2 * 8 * 64];  // h-partial accs: [fh][acc8][lane]

    const int tid   = threadIdx.x;
    const int layer = blockIdx.x >> 8;
    const int row   = blockIdx.x & 255;
    const int b = row >> 6, y = row & 63;

    const int wave = tid >> 6;
    const int L    = tid & 63;
    const int fh   = wave >> 1;     // f-half
    const int src  = wave & 1;      // 0 = x-side (epilogue owner), 1 = h-side
    const int c    = L & 15;
    const int q    = L >> 4;

    const bf16x8* wpkv = (const bf16x8*)(layer ? wpk2 : wpk1);
    const float*  bias = layer ? bias2 : bias1;

    // Register-resident B fragments: 9 taps x 4 gates for this (src, fh).
    bf16x8 wb[9][4];
    #pragma unroll
    for (int tap = 0; tap < 9; ++tap) {
        #pragma unroll
        for (int g = 0; g < 4; ++g)
            wb[tap][g] = wpkv[(((tap * 2 + src) * 8) + fh * 4 + g) * 64 + L];
    }

    float bv[4];
    #pragma unroll
    for (int g = 0; g < 4; ++g) bv[g] = bias[g * 32 + fh * 16 + c];

    float creg[4][4];                      // [Mtile][r] cell state, fp32
    #pragma unroll
    for (int i = 0; i < 4; ++i) {
        #pragma unroll
        for (int r = 0; r < 4; ++r) creg[i][r] = 0.f;
    }

    const size_t rowbase = ((size_t)b * 64 + y) * 64 * 32;   // row offset in plane

    for (int t = 0; t < 16; ++t) {
        // ---- dependency waits ----
        if (layer == 0) {
            if (t > 0) {
                if (y > 0)  waitflag(flag1 + row - 1, t);
                if (y < 63) waitflag(flag1 + row + 1, t);
            }
            if (t >= 2) {   // WAR throttle: L2 consumers of h1_{t-2} must be done
                waitflag(flag2 + row, t - 1);
                if (y > 0)  waitflag(flag2 + row - 1, t - 1);
                if (y < 63) waitflag(flag2 + row + 1, t - 1);
            }
        } else {
            waitflag(flag1 + row, t + 1);
            if (y > 0)  waitflag(flag1 + row - 1, t + 1);
            if (y < 63) waitflag(flag1 + row + 1, t + 1);
            if (t > 0) {
                if (y > 0)  waitflag(flag2 + row - 1, t);
                if (y < 63) waitflag(flag2 + row + 1, t);
            }
        }
        __threadfence();   // acquire: invalidate stale cached h lines

        // ---- stage halo tiles into LDS (all threads) ----
        const float*  x0b = nullptr;
        const __bf16* s0b = nullptr;
        const __bf16* s1b;
        if (layer == 0) {
            x0b = x + (((size_t)b * 16 + t) * 4096) * 32;
            s1b = h1b + (size_t)((t ^ 1) & 1) * PLANE;
        } else {
            s0b = h1b + (size_t)(t & 1) * PLANE;
            s1b = h2b + (size_t)((t ^ 1) & 1) * PLANE;
        }
        const int nch = t ? 1584 : 792;    // t=0: skip h staging entirely
        for (int i = tid; i < nch; i += 256) {
            const int sidx = (i >= 792);
            const int r2   = i - sidx * 792;
            const int g  = r2 & 3;
            const int rc = r2 >> 2;        // 0..197
            const int cc = rc % 66;
            const int dy = rc / 66;
            const int yy = y + dy - 1;
            const int xc = cc - 1;
            bf16x8 v = {};
            if (yy >= 0 && yy < 64 && xc >= 0 && xc < 64) {
                if (layer == 0 && sidx == 0) {
                    const float* p = x0b + (((size_t)yy * 64 + xc) * 32 + g * 8);
                    const float4 f0 = *(const float4*)p;
                    const float4 f1 = *(const float4*)(p + 4);
                    v[0] = (__bf16)f0.x; v[1] = (__bf16)f0.y;
                    v[2] = (__bf16)f0.z; v[3] = (__bf16)f0.w;
                    v[4] = (__bf16)f1.x; v[5] = (__bf16)f1.y;
                    v[6] = (__bf16)f1.z; v[7] = (__bf16)f1.w;
                } else {
                    const __bf16* p = (sidx ? s1b : s0b) +
                        (((size_t)b * 64 + yy) * 64 + xc) * 32 + g * 8;
                    v = *(const bf16x8*)p;
                }
            }
            *(bf16x8*)((sidx ? s_h : s_x) + (dy * 66 + cc) * 36 + g * 8) = v;
        }
        __syncthreads();

        const __bf16* sbase = src ? s_h : s_x;
        __bf16* hb_out = (layer ? h2b : h1b) + (size_t)(t & 1) * PLANE + rowbase;
        float* outp = layer ? (out + (((size_t)b * 16 + t) * 4096 + (size_t)y * 64) * 32)
                            : nullptr;

        // ---- two M-passes of 32 pixels each ----
        #pragma unroll
        for (int mp = 0; mp < 2; ++mp) {
            f32x4 acc[2][4];
            #pragma unroll
            for (int m2 = 0; m2 < 2; ++m2) {
                #pragma unroll
                for (int g = 0; g < 4; ++g) {
                    if (src == 0) acc[m2][g] = (f32x4){bv[g], bv[g], bv[g], bv[g]};
                    else          acc[m2][g] = (f32x4){0.f, 0.f, 0.f, 0.f};
                }
            }
            if (!(src == 1 && t == 0)) {
                #pragma unroll
                for (int tap = 0; tap < 9; ++tap) {
                    const int dyk = tap / 3, dxk = tap % 3;
                    const bf16x8 a0 = *(const bf16x8*)(sbase +
                        (dyk * 66 + mp * 32 + c + dxk) * 36 + q * 8);
                    const bf16x8 a1 = *(const bf16x8*)(sbase +
                        (dyk * 66 + mp * 32 + 16 + c + dxk) * 36 + q * 8);
                    acc[0][0] = __builtin_amdgcn_mfma_f32_16x16x32_bf16(a0, wb[tap][0], acc[0][0], 0, 0, 0);
                    acc[0][1] = __builtin_amdgcn_mfma_f32_16x16x32_bf16(a0, wb[tap][1], acc[0][1], 0, 0, 0);
                    acc[0][2] = __builtin_amdgcn_mfma_f32_16x16x32_bf16(a0, wb[tap][2], acc[0][2], 0, 0, 0);
                    acc[0][3] = __builtin_amdgcn_mfma_f32_16x16x32_bf16(a0, wb[tap][3], acc[0][3], 0, 0, 0);
                    acc[1][0] = __builtin_amdgcn_mfma_f32_16x16x32_bf16(a1, wb[tap][0], acc[1][0], 0, 0, 0);
                    acc[1][1] = __builtin_amdgcn_mfma_f32_16x16x32_bf16(a1, wb[tap][1], acc[1][1], 0, 0, 0);
                    acc[1][2] = __builtin_amdgcn_mfma_f32_16x16x32_bf16(a1, wb[tap][2], acc[1][2], 0, 0, 0);
                    acc[1][3] = __builtin_amdgcn_mfma_f32_16x16x32_bf16(a1, wb[tap][3], acc[1][3], 0, 0, 0);
                }
            }
            if (src == 1) {
                #pragma unroll
                for (int m2 = 0; m2 < 2; ++m2) {
                    #pragma unroll
                    for (int g = 0; g < 4; ++g)
                        s_red[(fh * 8 + m2 * 4 + g) * 64 + L] = acc[m2][g];
                }
            }
            __syncthreads();
            if (src == 0) {
                #pragma unroll
                for (int m2 = 0; m2 < 2; ++m2) {
                    const f32x4 zi = acc[m2][0] + s_red[(fh * 8 + m2 * 4 + 0) * 64 + L];
                    const f32x4 zf = acc[m2][1] + s_red[(fh * 8 + m2 * 4 + 1) * 64 + L];
                    const f32x4 zc = acc[m2][2] + s_red[(fh * 8 + m2 * 4 + 2) * 64 + L];
                    const f32x4 zo = acc[m2][3] + s_red[(fh * 8 + m2 * 4 + 3) * 64 + L];
                    #pragma unroll
                    for (int r = 0; r < 4; ++r) {
                        const float ig = fsigmoid(zi[r]);
                        const float fg = fsigmoid(zf[r]);
                        const float gg = ftanh(zc[r]);
                        const float og = fsigmoid(zo[r]);
                        const float cn = fg * creg[mp * 2 + m2][r] + ig * gg;
                        creg[mp * 2 + m2][r] = cn;
                        const float hv = og * ftanh(cn);
                        const int xw = mp * 32 + m2 * 16 + q * 4 + r;
                        const int fcol = fh * 16 + c;
                        hb_out[(size_t)xw * 32 + fcol] = (__bf16)hv;
                        if (layer) outp[(size_t)xw * 32 + fcol] = hv;
                    }
                }
            }
            __syncthreads();
        }

        // ---- publish ----
        __threadfence();
        __syncthreads();
        if (tid == 0) {
            __hip_atomic_store(layer ? (flag2 + row) : (flag1 + row), t + 1,
                               __ATOMIC_RELEASE, __HIP_MEMORY_SCOPE_AGENT);
        }
    }
}

extern "C" void kernel_launch(void* const* d_in, const int* in_sizes, int n_in,
                              void* d_out, int out_size, void* d_ws, size_t ws_size,
                              hipStream_t stream)
{
    const float* x   = (const float*)d_in[0];
    const float* k1  = (const float*)d_in[1];
    const float* rk1 = (const float*)d_in[2];
    const float* b1  = (const float*)d_in[3];
    const float* k2  = (const float*)d_in[4];
    const float* rk2 = (const float*)d_in[5];
    const float* b2  = (const float*)d_in[6];
    float* out = (float*)d_out;

    int*    flags = (int*)d_ws;                               // 512 ints
    __bf16* wpk1  = (__bf16*)((char*)d_ws + 2048);
    __bf16* wpk2  = wpk1 + WPK_ELEMS;
    __bf16* h1b   = wpk2 + WPK_ELEMS;
    __bf16* h2b   = h1b + 2 * PLANE;

    hipMemsetAsync(flags, 0, 2048, stream);
    pack_weights<<<(2 * WPK_ELEMS + 255) / 256, 256, 0, stream>>>(k1, rk1, k2, rk2, wpk1);

    clstm_persist<<<512, 256, 0, stream>>>(
        x, wpk1, wpk2, b1, b2, h1b, h2b, flags, flags + 256, out);
}

// Round 4
// 328.224 us; speedup vs baseline: 5.9297x; 5.9297x over previous
//
#include <hip/hip_runtime.h>

// ConvLSTM2D x2, fused-step launches. B=4 T=16 H=W=64 Cin=F=32, k=3 SAME.
// Launch j (j=0..16) computes {L1 step j, L2 step j-1} in one 512-block grid:
// both depend only on launch j-1's outputs, so sync = kernel boundary.
// Block = one row (b,y) of 64 pixels; waves = {src x/h} x {f-half}; each wave
// holds its 36 weight fragments (9 taps x 4 gates) in VGPRs for the step.

typedef __bf16 bf16x8 __attribute__((ext_vector_type(8)));
typedef float f32x4 __attribute__((ext_vector_type(4)));

#define WPK_ELEMS 73728   // 18 kchunks * 8 ntiles * 64 lanes * 8
#define PLANE 524288      // 4*64*64*32 elems (one parity plane)

__device__ __forceinline__ float fsigmoid(float z) {
    return 1.0f / (1.0f + __expf(-z));
}
__device__ __forceinline__ float ftanh(float z) {
    z = fminf(15.0f, fmaxf(-15.0f, z));
    float e = __expf(2.0f * z);
    return (e - 1.0f) / (e + 1.0f);
}

// Pack wk/wr (3,3,32,128) fp32 -> wpk[layer][cix][nt][lane][j2] bf16.
// cix = tap*2 + src (src0 = input kernel, src1 = recurrent kernel).
// col n' = nt*16 + (lane&15): gate = nt&3, f = (nt>>2)*16 + (lane&15).
__global__ __launch_bounds__(256) void pack_weights(
    const float* __restrict__ wk1, const float* __restrict__ wr1,
    const float* __restrict__ wk2, const float* __restrict__ wr2,
    __bf16* __restrict__ wpk)
{
    int i = blockIdx.x * 256 + threadIdx.x;
    if (i >= 2 * WPK_ELEMS) return;
    int layer = i / WPK_ELEMS;
    int r = i - layer * WPK_ELEMS;
    int j2 = r & 7;
    int L  = (r >> 3) & 63;
    int nt = (r >> 9) & 7;
    int cix = r >> 12;            // 0..17
    int tap = cix >> 1, src = cix & 1;
    int s = ((L >> 4) << 3) + j2;            // channel 0..31
    int gate = nt & 3;
    int f = ((nt >> 2) << 4) + (L & 15);
    int n = (gate << 5) + f;
    const float* w = layer ? (src ? wr2 : wk2) : (src ? wr1 : wk1);
    wpk[i] = (__bf16)w[(tap * 32 + s) * 128 + n];
}

__global__ __launch_bounds__(256, 2) void clstm_fused(
    const float* __restrict__ x,          // (4,16,64,64,32) fp32
    const __bf16* __restrict__ wpk1,
    const __bf16* __restrict__ wpk2,
    const float* __restrict__ bias1,
    const float* __restrict__ bias2,
    __bf16* __restrict__ h1b,             // 2 parity planes (4,64,64,32) bf16
    __bf16* __restrict__ h2b,             // 2 parity planes
    float* __restrict__ c1,               // (4,64,64,32) fp32
    float* __restrict__ c2,
    float* __restrict__ out,              // (4,16,64,64,32) fp32
    int j)
{
    __shared__ __bf16 s_x[3 * 66 * 36];   // src0 tile (x or h1_t), 36-ch padded
    __shared__ __bf16 s_h[3 * 66 * 36];   // src1 tile (h_{t-1})
    __shared__ f32x4  s_red[2 * 8 * 64];  // h-wave partials: [fh][acc8][lane]

    const int layer = blockIdx.x >> 8;
    const int t = layer ? (j - 1) : j;
    if (t < 0 || t > 15) return;

    const int tid = threadIdx.x;
    const int row = blockIdx.x & 255;
    const int b = row >> 6, y = row & 63;

    const int wave = tid >> 6;
    const int L    = tid & 63;
    const int fh   = wave >> 1;     // f-half
    const int src  = wave & 1;      // 0 = x-side (epilogue owner), 1 = h-side
    const int c    = L & 15;
    const int q    = L >> 4;

    const bf16x8* wpkv = (const bf16x8*)(layer ? wpk2 : wpk1);
    const float*  bias = layer ? bias2 : bias1;
    float* cbuf = layer ? c2 : c1;

    // Register-resident B fragments: 9 taps x 4 gates for this (src, fh).
    bf16x8 wb[9][4];
    #pragma unroll
    for (int tap = 0; tap < 9; ++tap) {
        #pragma unroll
        for (int g = 0; g < 4; ++g)
            wb[tap][g] = wpkv[(((tap * 2 + src) * 8) + fh * 4 + g) * 64 + L];
    }

    float bv[4];
    #pragma unroll
    for (int g = 0; g < 4; ++g) bv[g] = bias[g * 32 + fh * 16 + c];

    // ---- stage halo tiles into LDS (all threads) ----
    const float*  x0b = nullptr;
    const __bf16* s0b = nullptr;
    const __bf16* s1b;
    if (layer == 0) {
        x0b = x + (((size_t)b * 16 + t) * 4096) * 32;
        s1b = h1b + (size_t)((t ^ 1) & 1) * PLANE;
    } else {
        s0b = h1b + (size_t)(t & 1) * PLANE;
        s1b = h2b + (size_t)((t ^ 1) & 1) * PLANE;
    }
    const int nch = t ? 1584 : 792;    // t=0: skip h staging entirely
    for (int i = tid; i < nch; i += 256) {
        const int sidx = (i >= 792);
        const int r2   = i - sidx * 792;
        const int g  = r2 & 3;
        const int rc = r2 >> 2;        // 0..197
        const int cc = rc % 66;
        const int dy = rc / 66;
        const int yy = y + dy - 1;
        const int xc = cc - 1;
        bf16x8 v = {};
        if (yy >= 0 && yy < 64 && xc >= 0 && xc < 64) {
            if (layer == 0 && sidx == 0) {
                const float* p = x0b + (((size_t)yy * 64 + xc) * 32 + g * 8);
                const float4 f0 = *(const float4*)p;
                const float4 f1 = *(const float4*)(p + 4);
                v[0] = (__bf16)f0.x; v[1] = (__bf16)f0.y;
                v[2] = (__bf16)f0.z; v[3] = (__bf16)f0.w;
                v[4] = (__bf16)f1.x; v[5] = (__bf16)f1.y;
                v[6] = (__bf16)f1.z; v[7] = (__bf16)f1.w;
            } else {
                const __bf16* p = (sidx ? s1b : s0b) +
                    (((size_t)b * 64 + yy) * 64 + xc) * 32 + g * 8;
                v = *(const bf16x8*)p;
            }
        }
        *(bf16x8*)((sidx ? s_h : s_x) + (dy * 66 + cc) * 36 + g * 8) = v;
    }
    __syncthreads();

    const __bf16* sbase = src ? s_h : s_x;
    const size_t rowbase = ((size_t)b * 64 + y) * 64 * 32;
    __bf16* hb_out = (layer ? h2b : h1b) + (size_t)(t & 1) * PLANE + rowbase;
    float* outp = layer ? (out + (((size_t)b * 16 + t) * 4096 + (size_t)y * 64) * 32)
                        : nullptr;

    // ---- two M-passes of 32 pixels each ----
    #pragma unroll
    for (int mp = 0; mp < 2; ++mp) {
        f32x4 acc[2][4];
        #pragma unroll
        for (int m2 = 0; m2 < 2; ++m2) {
            #pragma unroll
            for (int g = 0; g < 4; ++g) {
                if (src == 0) acc[m2][g] = (f32x4){bv[g], bv[g], bv[g], bv[g]};
                else          acc[m2][g] = (f32x4){0.f, 0.f, 0.f, 0.f};
            }
        }
        if (!(src == 1 && t == 0)) {
            #pragma unroll
            for (int tap = 0; tap < 9; ++tap) {
                const int dyk = tap / 3, dxk = tap % 3;
                const bf16x8 a0 = *(const bf16x8*)(sbase +
                    (dyk * 66 + mp * 32 + c + dxk) * 36 + q * 8);
                const bf16x8 a1 = *(const bf16x8*)(sbase +
                    (dyk * 66 + mp * 32 + 16 + c + dxk) * 36 + q * 8);
                acc[0][0] = __builtin_amdgcn_mfma_f32_16x16x32_bf16(a0, wb[tap][0], acc[0][0], 0, 0, 0);
                acc[0][1] = __builtin_amdgcn_mfma_f32_16x16x32_bf16(a0, wb[tap][1], acc[0][1], 0, 0, 0);
                acc[0][2] = __builtin_amdgcn_mfma_f32_16x16x32_bf16(a0, wb[tap][2], acc[0][2], 0, 0, 0);
                acc[0][3] = __builtin_amdgcn_mfma_f32_16x16x32_bf16(a0, wb[tap][3], acc[0][3], 0, 0, 0);
                acc[1][0] = __builtin_amdgcn_mfma_f32_16x16x32_bf16(a1, wb[tap][0], acc[1][0], 0, 0, 0);
                acc[1][1] = __builtin_amdgcn_mfma_f32_16x16x32_bf16(a1, wb[tap][1], acc[1][1], 0, 0, 0);
                acc[1][2] = __builtin_amdgcn_mfma_f32_16x16x32_bf16(a1, wb[tap][2], acc[1][2], 0, 0, 0);
                acc[1][3] = __builtin_amdgcn_mfma_f32_16x16x32_bf16(a1, wb[tap][3], acc[1][3], 0, 0, 0);
            }
        }
        if (src == 1) {
            #pragma unroll
            for (int m2 = 0; m2 < 2; ++m2) {
                #pragma unroll
                for (int g = 0; g < 4; ++g)
                    s_red[(fh * 8 + m2 * 4 + g) * 64 + L] = acc[m2][g];
            }
        }
        __syncthreads();
        if (src == 0) {
            #pragma unroll
            for (int m2 = 0; m2 < 2; ++m2) {
                const f32x4 zi = acc[m2][0] + s_red[(fh * 8 + m2 * 4 + 0) * 64 + L];
                const f32x4 zf = acc[m2][1] + s_red[(fh * 8 + m2 * 4 + 1) * 64 + L];
                const f32x4 zc = acc[m2][2] + s_red[(fh * 8 + m2 * 4 + 2) * 64 + L];
                const f32x4 zo = acc[m2][3] + s_red[(fh * 8 + m2 * 4 + 3) * 64 + L];
                #pragma unroll
                for (int r = 0; r < 4; ++r) {
                    const int xw = mp * 32 + m2 * 16 + q * 4 + r;
                    const int fcol = fh * 16 + c;
                    const size_t cidx = rowbase + (size_t)xw * 32 + fcol;
                    const float ig = fsigmoid(zi[r]);
                    const float fg = fsigmoid(zf[r]);
                    const float gg = ftanh(zc[r]);
                    const float og = fsigmoid(zo[r]);
                    const float cold = t ? cbuf[cidx] : 0.0f;
                    const float cn = fg * cold + ig * gg;
                    cbuf[cidx] = cn;
                    const float hv = og * ftanh(cn);
                    hb_out[(size_t)xw * 32 + fcol] = (__bf16)hv;
                    if (layer) outp[(size_t)xw * 32 + fcol] = hv;
                }
            }
        }
        __syncthreads();
    }
}

extern "C" void kernel_launch(void* const* d_in, const int* in_sizes, int n_in,
                              void* d_out, int out_size, void* d_ws, size_t ws_size,
                              hipStream_t stream)
{
    const float* x   = (const float*)d_in[0];
    const float* k1  = (const float*)d_in[1];
    const float* rk1 = (const float*)d_in[2];
    const float* b1  = (const float*)d_in[3];
    const float* k2  = (const float*)d_in[4];
    const float* rk2 = (const float*)d_in[5];
    const float* b2  = (const float*)d_in[6];
    float* out = (float*)d_out;

    __bf16* wpk1 = (__bf16*)d_ws;
    __bf16* wpk2 = wpk1 + WPK_ELEMS;
    __bf16* h1b  = wpk2 + WPK_ELEMS;          // 2 parity planes bf16
    __bf16* h2b  = h1b + 2 * PLANE;
    float*  c1   = (float*)(h2b + 2 * PLANE); // fp32, 16B-aligned
    float*  c2   = c1 + PLANE;

    pack_weights<<<(2 * WPK_ELEMS + 255) / 256, 256, 0, stream>>>(k1, rk1, k2, rk2, wpk1);

    for (int j = 0; j <= 16; ++j) {
        clstm_fused<<<512, 256, 0, stream>>>(
            x, wpk1, wpk2, b1, b2, h1b, h2b, c1, c2, out, j);
    }
}